// Round 3
// baseline (339.518 us; speedup 1.0000x reference)
//
#include <hip/hip_runtime.h>

#define TD 256   // threads per block everywhere

typedef unsigned int uint;
typedef unsigned short ushort;

// ---- bf16 helpers (RNE pack, cheap unpack) ----
__device__ __forceinline__ ushort f2bf(float f) {
    uint u = __float_as_uint(f);
    u += 0x7fffu + ((u >> 16) & 1u);
    return (ushort)(u >> 16);
}
__device__ __forceinline__ float2 bfp2f(uint u) {
    float2 r;
    r.x = __uint_as_float(u << 16);
    r.y = __uint_as_float(u & 0xffff0000u);
    return r;
}

// ---------------- degree / CSR build ----------------

__global__ void k_count(const int* __restrict__ dst, int e, int* __restrict__ deg) {
    int i = blockIdx.x * TD + threadIdx.x;
    if (i < e) atomicAdd(&deg[dst[i]], 1);
}

// per-block sums of deg
__global__ void k_scanA(const int* __restrict__ deg, int n, int* __restrict__ bsum) {
    __shared__ int s[TD];
    int t = threadIdx.x;
    int i = blockIdx.x * TD + t;
    s[t] = (i < n) ? deg[i] : 0;
    __syncthreads();
    for (int off = TD / 2; off > 0; off >>= 1) {
        if (t < off) s[t] += s[t + off];
        __syncthreads();
    }
    if (t == 0) bsum[blockIdx.x] = s[0];
}

// exclusive scan of block sums (nb <= 256), in place
__global__ void k_scanB(int* __restrict__ bsum, int nb) {
    __shared__ int s[TD];
    int t = threadIdx.x;
    int v = (t < nb) ? bsum[t] : 0;
    s[t] = v;
    __syncthreads();
    for (int off = 1; off < TD; off <<= 1) {
        int u = (t >= off) ? s[t - off] : 0;
        __syncthreads();
        s[t] += u;
        __syncthreads();
    }
    if (t < nb) bsum[t] = s[t] - v;   // exclusive
}

// per-block exclusive scan + block offset -> rowStart, cursor; also dinv = rsqrt(deg+1)
__global__ void k_scanC(const int* __restrict__ deg, int n, const int* __restrict__ bsum,
                        int* __restrict__ rowStart, int* __restrict__ cursor,
                        float* __restrict__ dinv) {
    __shared__ int s[TD];
    int t = threadIdx.x;
    int i = blockIdx.x * TD + t;
    int v = (i < n) ? deg[i] : 0;
    s[t] = v;
    __syncthreads();
    for (int off = 1; off < TD; off <<= 1) {
        int u = (t >= off) ? s[t - off] : 0;
        __syncthreads();
        s[t] += u;
        __syncthreads();
    }
    if (i < n) {
        int rs = bsum[blockIdx.x] + s[t] - v;
        rowStart[i] = rs;
        cursor[i]   = rs;
        dinv[i]     = rsqrtf((float)(v + 1));   // +1 self-loop
    }
}

__global__ void k_fill(const int* __restrict__ src, const int* __restrict__ dst, int e,
                       int* __restrict__ cursor, int* __restrict__ csr) {
    int i = blockIdx.x * TD + threadIdx.x;
    if (i < e) {
        int d = dst[i];
        int slot = atomicAdd(&cursor[d], 1);
        csr[slot] = src[i];
    }
}

// FMA micro-tile helper: acc[0..3] += a.{x,y,z,w} dotted against b0..b3 rows
#define FMA4(ACC, A, B0, B1, B2, B3)                                      \
    ACC[0] += A.x * B0.x + A.y * B1.x + A.z * B2.x + A.w * B3.x;          \
    ACC[1] += A.x * B0.y + A.y * B1.y + A.z * B2.y + A.w * B3.y;          \
    ACC[2] += A.x * B0.z + A.y * B1.z + A.z * B2.z + A.w * B3.z;          \
    ACC[3] += A.x * B0.w + A.y * B1.w + A.z * B2.w + A.w * B3.w;

// ---------------- xws = bf16( (x @ Wg) * dinv[row] ) ----------------
// 32 rows x 128 cols per block; W staged in 16KB chunks with register prefetch.
__global__ __launch_bounds__(256) void k_xw(const float* __restrict__ x,
                                            const float* __restrict__ W,
                                            const float* __restrict__ dinv,
                                            ushort* __restrict__ xws, int n) {
    __shared__ float sX[32][132];   // [r][k] full-K tile, 16.9 KB
    __shared__ float sW[32 * 128];  // 16 KB chunk
    int t = threadIdx.x;
    int row0 = blockIdx.x * 32;
    int rt = t >> 5;   // 0..7 -> rows rt*4..+3
    int ct = t & 31;   // 0..31 -> cols ct*4..+3
    float acc[4][4] = {};

    // preload W chunk 0 into regs (in flight during X staging)
    float4 w0 = ((const float4*)W)[t];
    float4 w1 = ((const float4*)W)[t + 256];
    float4 w2 = ((const float4*)W)[t + 512];
    float4 w3 = ((const float4*)W)[t + 768];

    // stage full X tile: 32 rows x 32 quads, natural layout
    for (int i = t; i < 1024; i += TD) {
        int r = i >> 5, kq = i & 31;
        int gr = row0 + r;
        float4 v = (gr < n) ? ((const float4*)x)[(size_t)gr * 32 + kq]
                            : make_float4(0.f, 0.f, 0.f, 0.f);
        *(float4*)&sX[r][kq * 4] = v;
    }

    for (int kc = 0; kc < 128; kc += 32) {
        if (kc) __syncthreads();          // prev chunk's compute done before overwrite
        ((float4*)sW)[t]       = w0;
        ((float4*)sW)[t + 256] = w1;
        ((float4*)sW)[t + 512] = w2;
        ((float4*)sW)[t + 768] = w3;
        if (kc + 32 < 128) {              // prefetch next chunk (overlaps compute below)
            int base = (kc + 32) * 32;
            w0 = ((const float4*)W)[base + t];
            w1 = ((const float4*)W)[base + t + 256];
            w2 = ((const float4*)W)[base + t + 512];
            w3 = ((const float4*)W)[base + t + 768];
        }
        __syncthreads();                  // sW (and on first iter sX) visible
        #pragma unroll
        for (int k4 = 0; k4 < 32; k4 += 4) {
            float4 a0 = *(const float4*)&sX[rt * 4 + 0][kc + k4];
            float4 a1 = *(const float4*)&sX[rt * 4 + 1][kc + k4];
            float4 a2 = *(const float4*)&sX[rt * 4 + 2][kc + k4];
            float4 a3 = *(const float4*)&sX[rt * 4 + 3][kc + k4];
            float4 b0 = *(const float4*)&sW[(k4 + 0) * 128 + ct * 4];
            float4 b1 = *(const float4*)&sW[(k4 + 1) * 128 + ct * 4];
            float4 b2 = *(const float4*)&sW[(k4 + 2) * 128 + ct * 4];
            float4 b3 = *(const float4*)&sW[(k4 + 3) * 128 + ct * 4];
            FMA4(acc[0], a0, b0, b1, b2, b3);
            FMA4(acc[1], a1, b0, b1, b2, b3);
            FMA4(acc[2], a2, b0, b1, b2, b3);
            FMA4(acc[3], a3, b0, b1, b2, b3);
        }
    }
    #pragma unroll
    for (int i = 0; i < 4; i++) {
        int gr = row0 + rt * 4 + i;
        if (gr < n) {
            float dv = dinv[gr];
            ushort4 o;
            o.x = f2bf(acc[i][0] * dv);
            o.y = f2bf(acc[i][1] * dv);
            o.z = f2bf(acc[i][2] * dv);
            o.w = f2bf(acc[i][3] * dv);
            ((ushort4*)xws)[(size_t)gr * 32 + ct] = o;   // bf16 row: 256 B
        }
    }
}

// ---------------- aggregation: one wave per node, bf16 gather, 8-way unrolled ----
// agg = dinv[d] * (xws[d] + sum_{s in in(d)} xws[s]); h0 = relu(agg+bg) + x
__global__ __launch_bounds__(256) void k_agg(const uint* __restrict__ xws,
                                             const float* __restrict__ x,
                                             const int* __restrict__ rowStart,
                                             const int* __restrict__ deg,
                                             const int* __restrict__ csr,
                                             const float* __restrict__ dinv,
                                             const float* __restrict__ bg,
                                             float* __restrict__ h0, int n) {
    int wave = threadIdx.x >> 6;
    int lane = threadIdx.x & 63;
    int node = blockIdx.x * 4 + wave;
    if (node >= n) return;
    // lane covers elems [2*lane, 2*lane+1]; one uint = 2 bf16
    float2 A0, A1 = {0.f,0.f}, A2 = {0.f,0.f}, A3 = {0.f,0.f};
    A0 = bfp2f(xws[(size_t)node * 64 + lane]);    // self-loop term
    int st = rowStart[node];
    int cnt = deg[node];
    int i = 0;
    for (; i + 8 <= cnt; i += 8) {
        int s0 = csr[st + i + 0], s1 = csr[st + i + 1];
        int s2 = csr[st + i + 2], s3 = csr[st + i + 3];
        int s4 = csr[st + i + 4], s5 = csr[st + i + 5];
        int s6 = csr[st + i + 6], s7 = csr[st + i + 7];
        uint u0 = xws[(size_t)s0 * 64 + lane];
        uint u1 = xws[(size_t)s1 * 64 + lane];
        uint u2 = xws[(size_t)s2 * 64 + lane];
        uint u3 = xws[(size_t)s3 * 64 + lane];
        uint u4 = xws[(size_t)s4 * 64 + lane];
        uint u5 = xws[(size_t)s5 * 64 + lane];
        uint u6 = xws[(size_t)s6 * 64 + lane];
        uint u7 = xws[(size_t)s7 * 64 + lane];
        float2 v0 = bfp2f(u0), v1 = bfp2f(u1), v2 = bfp2f(u2), v3 = bfp2f(u3);
        float2 v4 = bfp2f(u4), v5 = bfp2f(u5), v6 = bfp2f(u6), v7 = bfp2f(u7);
        A0.x += v0.x; A0.y += v0.y;  A1.x += v1.x; A1.y += v1.y;
        A2.x += v2.x; A2.y += v2.y;  A3.x += v3.x; A3.y += v3.y;
        A0.x += v4.x; A0.y += v4.y;  A1.x += v5.x; A1.y += v5.y;
        A2.x += v6.x; A2.y += v6.y;  A3.x += v7.x; A3.y += v7.y;
    }
    for (; i < cnt; i++) {
        int s = csr[st + i];
        float2 v = bfp2f(xws[(size_t)s * 64 + lane]);
        A0.x += v.x; A0.y += v.y;
    }
    float2 acc;
    acc.x = (A0.x + A1.x) + (A2.x + A3.x);
    acc.y = (A0.y + A1.y) + (A2.y + A3.y);
    float dv = dinv[node];
    float2 b = ((const float2*)bg)[lane];
    float2 xv = ((const float2*)x)[(size_t)node * 64 + lane];
    float2 o;
    o.x = fmaxf(acc.x * dv + b.x, 0.f) + xv.x;
    o.y = fmaxf(acc.y * dv + b.y, 0.f) + xv.y;
    ((float2*)h0)[(size_t)node * 64 + lane] = o;
}

// ---------------- fused MLP: 32 rows per block, register-prefetched weights ----
__global__ __launch_bounds__(256) void k_mlp(const float* __restrict__ h0g,
                                             const float* __restrict__ W1, const float* __restrict__ b1,
                                             const float* __restrict__ W2, const float* __restrict__ b2,
                                             const float* __restrict__ W3, const float* __restrict__ b3,
                                             float* __restrict__ out, int n) {
    __shared__ float sh0[32][132];  // 16.9 KB [r][k]; overlaid by sh2t after stage 1
    __shared__ float sW[32 * 128];  // 16 KB weight chunk
    __shared__ float sh1[32][132];  // 16.9 KB [r][k]
    float* sh2t = &sh0[0][0];       // overlay: [64][36] = 2304 floats <= 4224 avail
    int t = threadIdx.x;
    int row0 = blockIdx.x * 32;

    // preload W1 chunk 0 into regs
    float4 w0 = ((const float4*)W1)[t];
    float4 w1 = ((const float4*)W1)[t + 256];
    float4 w2 = ((const float4*)W1)[t + 512];
    float4 w3 = ((const float4*)W1)[t + 768];

    // stage h0 tile: 32 rows x 32 quads, natural layout
    for (int i = t; i < 1024; i += TD) {
        int r = i >> 5, kq = i & 31;
        int gr = row0 + r;
        float4 v = (gr < n) ? ((const float4*)h0g)[(size_t)gr * 32 + kq]
                            : make_float4(0.f, 0.f, 0.f, 0.f);
        *(float4*)&sh0[r][kq * 4] = v;
    }

    // ---- stage 1: [32x128] @ W1[128x128], 4x4 micro-tile
    int rt = t >> 5;   // 0..7
    int ct = t & 31;   // 0..31
    float acc1[4][4] = {};
    for (int kc = 0; kc < 128; kc += 32) {
        if (kc) __syncthreads();
        ((float4*)sW)[t]       = w0;
        ((float4*)sW)[t + 256] = w1;
        ((float4*)sW)[t + 512] = w2;
        ((float4*)sW)[t + 768] = w3;
        if (kc + 32 < 128) {
            int base = (kc + 32) * 32;
            w0 = ((const float4*)W1)[base + t];
            w1 = ((const float4*)W1)[base + t + 256];
            w2 = ((const float4*)W1)[base + t + 512];
            w3 = ((const float4*)W1)[base + t + 768];
        } else {            // prefetch W2 chunk 0 instead
            w0 = ((const float4*)W2)[t];
            w1 = ((const float4*)W2)[t + 256];
            w2 = ((const float4*)W2)[t + 512];
            w3 = ((const float4*)W2)[t + 768];
        }
        __syncthreads();
        #pragma unroll
        for (int k4 = 0; k4 < 32; k4 += 4) {
            float4 a0 = *(const float4*)&sh0[rt * 4 + 0][kc + k4];
            float4 a1 = *(const float4*)&sh0[rt * 4 + 1][kc + k4];
            float4 a2 = *(const float4*)&sh0[rt * 4 + 2][kc + k4];
            float4 a3 = *(const float4*)&sh0[rt * 4 + 3][kc + k4];
            float4 q0 = *(const float4*)&sW[(k4 + 0) * 128 + ct * 4];
            float4 q1 = *(const float4*)&sW[(k4 + 1) * 128 + ct * 4];
            float4 q2 = *(const float4*)&sW[(k4 + 2) * 128 + ct * 4];
            float4 q3 = *(const float4*)&sW[(k4 + 3) * 128 + ct * 4];
            FMA4(acc1[0], a0, q0, q1, q2, q3);
            FMA4(acc1[1], a1, q0, q1, q2, q3);
            FMA4(acc1[2], a2, q0, q1, q2, q3);
            FMA4(acc1[3], a3, q0, q1, q2, q3);
        }
    }
    {
        float4 bb = *(const float4*)&b1[ct * 4];
        #pragma unroll
        for (int i = 0; i < 4; i++) {
            float4 o;
            o.x = fmaxf(acc1[i][0] + bb.x, 0.f);
            o.y = fmaxf(acc1[i][1] + bb.y, 0.f);
            o.z = fmaxf(acc1[i][2] + bb.z, 0.f);
            o.w = fmaxf(acc1[i][3] + bb.w, 0.f);
            *(float4*)&sh1[rt * 4 + i][ct * 4] = o;
        }
    }

    // ---- stage 2: [32x128] @ W2[128x64]; chunks of 64 k-rows (16 KB)
    int rt2 = t >> 4;  // 0..15 -> rows rt2*2..+1
    int ct2 = t & 15;  // 0..15 -> cols ct2*4..+3
    float acc2[2][4] = {};
    for (int c = 0; c < 2; c++) {
        __syncthreads();   // c=0: sh1 writes + prev sW reads done; c=1: chunk0 compute done
        ((float4*)sW)[t]       = w0;
        ((float4*)sW)[t + 256] = w1;
        ((float4*)sW)[t + 512] = w2;
        ((float4*)sW)[t + 768] = w3;
        if (c == 0) {       // prefetch W2 chunk 1
            w0 = ((const float4*)W2)[t + 1024];
            w1 = ((const float4*)W2)[t + 1280];
            w2 = ((const float4*)W2)[t + 1536];
            w3 = ((const float4*)W2)[t + 1792];
        }
        __syncthreads();
        #pragma unroll
        for (int k4 = 0; k4 < 64; k4 += 4) {
            float4 a0 = *(const float4*)&sh1[rt2 * 2 + 0][c * 64 + k4];
            float4 a1 = *(const float4*)&sh1[rt2 * 2 + 1][c * 64 + k4];
            float4 q0 = *(const float4*)&sW[(k4 + 0) * 64 + ct2 * 4];
            float4 q1 = *(const float4*)&sW[(k4 + 1) * 64 + ct2 * 4];
            float4 q2 = *(const float4*)&sW[(k4 + 2) * 64 + ct2 * 4];
            float4 q3 = *(const float4*)&sW[(k4 + 3) * 64 + ct2 * 4];
            FMA4(acc2[0], a0, q0, q1, q2, q3);
            FMA4(acc2[1], a1, q0, q1, q2, q3);
        }
    }
    {
        float4 bb = *(const float4*)&b2[ct2 * 4];
        __syncthreads();   // stage-2 reads done; sh2t overlays sh0 (dead)
        #pragma unroll
        for (int i = 0; i < 2; i++) {
            int r = rt2 * 2 + i;
            sh2t[(ct2 * 4 + 0) * 36 + r] = fmaxf(acc2[i][0] + bb.x, 0.f);
            sh2t[(ct2 * 4 + 1) * 36 + r] = fmaxf(acc2[i][1] + bb.y, 0.f);
            sh2t[(ct2 * 4 + 2) * 36 + r] = fmaxf(acc2[i][2] + bb.z, 0.f);
            sh2t[(ct2 * 4 + 3) * 36 + r] = fmaxf(acc2[i][3] + bb.w, 0.f);
        }
    }
    __syncthreads();

    // ---- stage 3: 32 rows x 2 cols
    if (t < 64) {
        int r = t >> 1, c = t & 1;
        float acc = b3[c];
        #pragma unroll
        for (int k = 0; k < 64; k++)
            acc += sh2t[k * 36 + r] * W3[k * 2 + c];
        int gr = row0 + r;
        if (gr < n) out[(size_t)c * n + gr] = acc;
    }
}

// ---------------- host launcher ----------------

extern "C" void kernel_launch(void* const* d_in, const int* in_sizes, int n_in,
                              void* d_out, int out_size, void* d_ws, size_t ws_size,
                              hipStream_t stream) {
    const float* x  = (const float*)d_in[0];
    const int*   ei = (const int*)d_in[1];
    const float* Wg = (const float*)d_in[2];
    const float* bg = (const float*)d_in[3];
    const float* W1 = (const float*)d_in[4];
    const float* b1 = (const float*)d_in[5];
    const float* W2 = (const float*)d_in[6];
    const float* b2 = (const float*)d_in[7];
    const float* W3 = (const float*)d_in[8];
    const float* b3 = (const float*)d_in[9];
    float* out = (float*)d_out;

    int n = in_sizes[0] / 128;
    int e = in_sizes[1] / 2;
    const int* src = ei;
    const int* dst = ei + e;

    // workspace carve-up (256B aligned)
    char* ws = (char*)d_ws;
    size_t off = 0;
    auto alloc = [&](size_t bytes) -> void* {
        void* p = ws + off;
        off = (off + bytes + 255) & ~(size_t)255;
        return p;
    };
    int*    deg      = (int*)alloc(sizeof(int) * (size_t)n);
    int*    rowStart = (int*)alloc(sizeof(int) * (size_t)n);
    int*    cursor   = (int*)alloc(sizeof(int) * (size_t)n);
    float*  dinv     = (float*)alloc(sizeof(float) * (size_t)n);
    int*    bsum     = (int*)alloc(sizeof(int) * 1024);
    int*    csr      = (int*)alloc(sizeof(int) * (size_t)e);
    ushort* xws      = (ushort*)alloc(sizeof(ushort) * (size_t)n * 128);
    float*  h0       = (float*)alloc(sizeof(float) * (size_t)n * 128);
    (void)ws_size; (void)n_in; (void)out_size;

    int nb = (n + TD - 1) / TD;      // 196 for n=50000 (must be <= 256 for k_scanB)
    int eb = (e + TD - 1) / TD;

    hipMemsetAsync(deg, 0, sizeof(int) * (size_t)n, stream);
    hipLaunchKernelGGL(k_count,    dim3(eb), dim3(TD), 0, stream, dst, e, deg);
    hipLaunchKernelGGL(k_scanA,    dim3(nb), dim3(TD), 0, stream, deg, n, bsum);
    hipLaunchKernelGGL(k_scanB,    dim3(1),  dim3(TD), 0, stream, bsum, nb);
    hipLaunchKernelGGL(k_scanC,    dim3(nb), dim3(TD), 0, stream, deg, n, bsum, rowStart, cursor, dinv);
    hipLaunchKernelGGL(k_fill,     dim3(eb), dim3(TD), 0, stream, src, dst, e, cursor, csr);
    hipLaunchKernelGGL(k_xw,       dim3((n + 31) / 32), dim3(TD), 0, stream, x, Wg, dinv, xws, n);
    hipLaunchKernelGGL(k_agg,      dim3((n + 3) / 4),   dim3(TD), 0, stream, (const uint*)xws, x, rowStart, deg, csr, dinv, bg, h0, n);
    hipLaunchKernelGGL(k_mlp,      dim3((n + 31) / 32), dim3(TD), 0, stream, h0, W1, b1, W2, b2, W3, b3, out, n);
}